// Round 7
// baseline (16817.686 us; speedup 1.0000x reference)
//
#include <hip/hip_runtime.h>
#include <math.h>

typedef unsigned short u16;
typedef float f32x4 __attribute__((ext_vector_type(4)));
typedef short s16x8 __attribute__((ext_vector_type(8)));

#define D_MODEL 1024
#define NH 16
#define DK 64
#define DFF 4096
#define BB 4
#define SS 2048
#define ROWS (BB*SS)   // 8192
#define MiB 1048576ull
#define BHSZ 4194304ull   // floats per att[bh] block (2048*2048)
#define QKS  131072ull    // floats per bh slice of q/k (2048*64)

static __device__ __forceinline__ float bf2f(u16 v){
  union{unsigned u; float f;} x; x.u = ((unsigned)v)<<16; return x.f;
}
static __device__ __forceinline__ u16 f2bf(float f){
  union{float f; unsigned u;} x; x.f=f;
  unsigned r = x.u + 0x7fffu + ((x.u>>16)&1u);
  return (u16)(r>>16);
}
static __device__ __forceinline__ double softplus64(float gf){
  double g = (double)gf;
  return (g > 0.0) ? g + log1p(exp(-g)) : log1p(exp(g));
}

// -------------------------------------------------- transpose + f32->bf16 split
// in f32 [R][C] -> bf16 [C][R]: oh (hi), om (mid, opt), ol (lo, opt)
__global__ __launch_bounds__(256) void twc(const float* __restrict__ in,
    u16* __restrict__ oh, u16* __restrict__ om, u16* __restrict__ ol, int R, int C){
  __shared__ float t[32][33];
  int c0 = blockIdx.x*32, r0 = blockIdx.y*32;
  int tx = threadIdx.x & 31, ty = threadIdx.x >> 5;
  for (int i=ty; i<32; i+=8) t[i][tx] = in[(size_t)(r0+i)*C + c0 + tx];
  __syncthreads();
  for (int i=ty; i<32; i+=8){
    float x = t[tx][i];
    u16 h = f2bf(x);
    size_t o = (size_t)(c0+i)*R + r0 + tx;
    oh[o] = h;
    if (om){
      float r1 = x - bf2f(h);
      u16 m = f2bf(r1);
      om[o] = m;
      if (ol){ float r2 = r1 - bf2f(m); ol[o] = f2bf(r2); }
    }
  }
}

// -------------------------------------------------- f32 copy
__global__ __launch_bounds__(256) void copyf(float* __restrict__ dst,
                                             const float* __restrict__ src, long long n){
  long long i = (long long)blockIdx.x*256 + threadIdx.x;
  long long stride = (long long)gridDim.x*256;
  for (; i < n; i += stride) dst[i] = src[i];
}

// -------------------------------------------------- triple-split GEMM (Q/K proj)
// o[head layout f32] = A(f32)[M,K] @ B^T + bias; B pre-split hi/mid/lo bf16 [N][K].
__global__ __launch_bounds__(256) void gemm3(
    const float* __restrict__ A, const u16* __restrict__ Bh,
    const u16* __restrict__ Bm, const u16* __restrict__ Bl,
    const float* __restrict__ bias, int M, int N, int K, float* __restrict__ o)
{
  __shared__ u16 lAh[128*32], lAm[128*32], lAl[128*32];
  __shared__ u16 lBh[128*32], lBm[128*32], lBl[128*32];
  const int tid = threadIdx.x, wid = tid>>6, L = tid&63;
  const int m0 = blockIdx.y*128, n0 = blockIdx.x*128;
  const int wm = (wid>>1)*64, wn = (wid&1)*64;
  f32x4 acc[4][4] = {};
  const int srow = wid*32 + (L>>2);
  const int scol = (L&3)*8;
  for (int kt=0; kt<K; kt+=32){
    s16x8 ah[2], am[2], al[2], vbh[2], vbm[2], vbl[2];
    #pragma unroll
    for (int rr=0; rr<2; rr++){
      const float* ap = &A[(size_t)(m0 + srow + rr*16)*K + kt + scol];
      #pragma unroll
      for (int e=0;e<8;e++){
        float x = ap[e];
        u16 hh = f2bf(x); float r1 = x - bf2f(hh);
        u16 mm = f2bf(r1); float r2 = r1 - bf2f(mm);
        ah[rr][e] = (short)hh; am[rr][e] = (short)mm; al[rr][e] = (short)f2bf(r2);
      }
      const size_t bo = (size_t)(n0 + srow + rr*16)*K + kt + scol;
      vbh[rr] = *(const s16x8*)&Bh[bo];
      vbm[rr] = *(const s16x8*)&Bm[bo];
      vbl[rr] = *(const s16x8*)&Bl[bo];
    }
    __syncthreads();
    #pragma unroll
    for (int rr=0; rr<2; rr++){
      const int ro = (srow + rr*16)*32 + scol;
      *(s16x8*)&lAh[ro] = ah[rr]; *(s16x8*)&lAm[ro] = am[rr]; *(s16x8*)&lAl[ro] = al[rr];
      *(s16x8*)&lBh[ro] = vbh[rr]; *(s16x8*)&lBm[ro] = vbm[rr]; *(s16x8*)&lBl[ro] = vbl[rr];
    }
    __syncthreads();
    const int lro = (L&15)*32 + (L>>4)*8;
    s16x8 afh[4], afm[4], afl[4], bfh[4], bfm[4], bfl[4];
    #pragma unroll
    for (int t=0;t<4;t++){
      afh[t] = *(const s16x8*)&lAh[(wm + t*16)*32 + lro];
      afm[t] = *(const s16x8*)&lAm[(wm + t*16)*32 + lro];
      afl[t] = *(const s16x8*)&lAl[(wm + t*16)*32 + lro];
      bfh[t] = *(const s16x8*)&lBh[(wn + t*16)*32 + lro];
      bfm[t] = *(const s16x8*)&lBm[(wn + t*16)*32 + lro];
      bfl[t] = *(const s16x8*)&lBl[(wn + t*16)*32 + lro];
    }
    #pragma unroll
    for (int mt=0;mt<4;mt++)
      #pragma unroll
      for (int nt=0;nt<4;nt++){
        f32x4 a2 = acc[mt][nt];
        a2 = __builtin_amdgcn_mfma_f32_16x16x32_bf16(afl[mt], bfh[nt], a2, 0,0,0);
        a2 = __builtin_amdgcn_mfma_f32_16x16x32_bf16(afm[mt], bfm[nt], a2, 0,0,0);
        a2 = __builtin_amdgcn_mfma_f32_16x16x32_bf16(afh[mt], bfl[nt], a2, 0,0,0);
        a2 = __builtin_amdgcn_mfma_f32_16x16x32_bf16(afm[mt], bfh[nt], a2, 0,0,0);
        a2 = __builtin_amdgcn_mfma_f32_16x16x32_bf16(afh[mt], bfm[nt], a2, 0,0,0);
        a2 = __builtin_amdgcn_mfma_f32_16x16x32_bf16(afh[mt], bfh[nt], a2, 0,0,0);
        acc[mt][nt] = a2;
      }
  }
  #pragma unroll
  for (int mt=0;mt<4;mt++)
    #pragma unroll
    for (int nt=0;nt<4;nt++){
      const int gn = n0 + wn + nt*16 + (L&15);
      const float bvv = bias[gn];
      const int gmb = m0 + wm + mt*16 + (L>>4)*4;
      const int h = gn>>6, d = gn&63;
      #pragma unroll
      for (int r=0;r<4;r++){
        const int gm = gmb + r, b = gm>>11, s = gm&2047;
        o[((size_t)(b*NH+h)*SS + s)*DK + d] = acc[mt][nt][r] + bvv;
      }
    }
}

// -------------------------------------------------- pair-split GEMM (~f32 quality)
// mode 0: f32 [M,N]   mode 1: relu f32 [M,N]   mode 2: f32 head layout
__global__ __launch_bounds__(256) void gemm2(
    const float* __restrict__ A, const u16* __restrict__ Bh, const u16* __restrict__ Bl,
    const float* __restrict__ bias, int M, int N, int K, int mode, float* __restrict__ o)
{
  __shared__ u16 lAh[128*32], lAl[128*32], lBh[128*32], lBl[128*32];
  const int tid = threadIdx.x, wid = tid>>6, L = tid&63;
  const int m0 = blockIdx.y*128, n0 = blockIdx.x*128;
  const int wm = (wid>>1)*64, wn = (wid&1)*64;
  f32x4 acc[4][4] = {};
  const int srow = wid*32 + (L>>2);
  const int scol = (L&3)*8;
  for (int kt=0; kt<K; kt+=32){
    s16x8 ah[2], al[2], vbh[2], vbl[2];
    #pragma unroll
    for (int rr=0; rr<2; rr++){
      const float* ap = &A[(size_t)(m0 + srow + rr*16)*K + kt + scol];
      #pragma unroll
      for (int e=0;e<8;e++){
        float x = ap[e];
        u16 hh = f2bf(x);
        ah[rr][e] = (short)hh;
        al[rr][e] = (short)f2bf(x - bf2f(hh));
      }
      const size_t bo = (size_t)(n0 + srow + rr*16)*K + kt + scol;
      vbh[rr] = *(const s16x8*)&Bh[bo];
      vbl[rr] = *(const s16x8*)&Bl[bo];
    }
    __syncthreads();
    #pragma unroll
    for (int rr=0; rr<2; rr++){
      const int ro = (srow + rr*16)*32 + scol;
      *(s16x8*)&lAh[ro] = ah[rr]; *(s16x8*)&lAl[ro] = al[rr];
      *(s16x8*)&lBh[ro] = vbh[rr]; *(s16x8*)&lBl[ro] = vbl[rr];
    }
    __syncthreads();
    const int lro = (L&15)*32 + (L>>4)*8;
    s16x8 afh[4], afl[4], bfh[4], bfl[4];
    #pragma unroll
    for (int t=0;t<4;t++){
      afh[t] = *(const s16x8*)&lAh[(wm + t*16)*32 + lro];
      afl[t] = *(const s16x8*)&lAl[(wm + t*16)*32 + lro];
      bfh[t] = *(const s16x8*)&lBh[(wn + t*16)*32 + lro];
      bfl[t] = *(const s16x8*)&lBl[(wn + t*16)*32 + lro];
    }
    #pragma unroll
    for (int mt=0;mt<4;mt++)
      #pragma unroll
      for (int nt=0;nt<4;nt++){
        f32x4 a2 = acc[mt][nt];
        a2 = __builtin_amdgcn_mfma_f32_16x16x32_bf16(afl[mt], bfh[nt], a2, 0,0,0);
        a2 = __builtin_amdgcn_mfma_f32_16x16x32_bf16(afh[mt], bfl[nt], a2, 0,0,0);
        a2 = __builtin_amdgcn_mfma_f32_16x16x32_bf16(afh[mt], bfh[nt], a2, 0,0,0);
        acc[mt][nt] = a2;
      }
  }
  #pragma unroll
  for (int mt=0;mt<4;mt++)
    #pragma unroll
    for (int nt=0;nt<4;nt++){
      const int gn = n0 + wn + nt*16 + (L&15);
      const float bvv = bias[gn];
      const int gmb = m0 + wm + mt*16 + (L>>4)*4;
      #pragma unroll
      for (int r=0;r<4;r++){
        const int gm = gmb + r;
        float v = acc[mt][nt][r] + bvv;
        if (mode==0)      o[(size_t)gm*N + gn] = v;
        else if (mode==1) o[(size_t)gm*N + gn] = fmaxf(v, 0.f);
        else {
          const int b = gm>>11, s = gm&2047, h = gn>>6, d = gn&63;
          o[((size_t)(b*NH+h)*SS + s)*DK + d] = v;
        }
      }
    }
}

// -------------------------------------------------- attention row kernel
// f64 scores/softmax. q/k slices: ptr + blockIdx.y*qs; absolute bh = bh0+blockIdx.y.
// wa: write att row (f32, zero upper). wc: PV -> ctx (f32, concat layout).
__global__ __launch_bounds__(256) void attn_row(
  const float* __restrict__ q, const float* __restrict__ k, long long qs,
  int bh0, int row0,
  const float* __restrict__ vb, const float* __restrict__ gammas,
  float* __restrict__ att, float* __restrict__ ctx, int wa, int wc)
{
  __shared__ double sq[64];
  __shared__ double p[SS];
  __shared__ double red[4];
  __shared__ float cpart[4][64];
  const int i = row0 + blockIdx.x;
  const int bh = bh0 + blockIdx.y, h = bh&15, b = bh>>4;
  const int t = threadIdx.x, wid = t>>6, L = t&63;
  const double sp = softplus64(gammas[h]);
  if (t < 64) sq[t] = (double)q[(size_t)blockIdx.y*qs + (size_t)i*DK + t];
  __syncthreads();

  double lmax = -1e300;
  for (int j = t; j <= i; j += 256){
    const float* kr = &k[(size_t)blockIdx.y*qs + (size_t)j*DK];
    double a0=0.0, a1=0.0, a2=0.0, a3=0.0;
    #pragma unroll
    for (int d=0; d<64; d+=4){
      a0 = fma((double)kr[d+0], sq[d+0], a0);
      a1 = fma((double)kr[d+1], sq[d+1], a1);
      a2 = fma((double)kr[d+2], sq[d+2], a2);
      a3 = fma((double)kr[d+3], sq[d+3], a3);
    }
    const double dot = (a0+a1)+(a2+a3);
    double eff = exp((double)(i-j) * (1.0/21.0) * sp);
    eff = (eff < 1e5) ? eff : 1e5;
    const double s = dot * 0.125 * eff;
    p[j] = s;
    lmax = (lmax > s) ? lmax : s;
  }
  #pragma unroll
  for (int m2=1;m2<64;m2<<=1){ double o2 = __shfl_xor(lmax,m2,64); lmax = (lmax>o2)?lmax:o2; }
  if (L==0) red[wid] = lmax;
  __syncthreads();
  double m = red[0];
  m = (m>red[1])?m:red[1]; m = (m>red[2])?m:red[2]; m = (m>red[3])?m:red[3];
  __syncthreads();
  double lsum = 0.0;
  for (int j = t; j <= i; j += 256){
    double e = exp(p[j] - m);
    p[j] = e;
    lsum += e;
  }
  #pragma unroll
  for (int m2=1;m2<64;m2<<=1) lsum += __shfl_xor(lsum,m2,64);
  if (L==0) red[wid] = lsum;
  __syncthreads();
  const double inv = 1.0 / (red[0]+red[1]+red[2]+red[3]);
  for (int j = t; j <= i; j += 256) p[j] *= inv;
  __syncthreads();

  if (wa){
    float* rb = &att[((size_t)bh*SS + i)*SS];
    for (int j = t; j < SS; j += 256)
      rb[j] = (j <= i) ? (float)p[j] : 0.f;
  }
  if (wc){
    const int gg = t>>6, d = t&63;
    float a = 0.f;
    for (int j = gg; j <= i; j += 4)
      a = fmaf((float)p[j], vb[((size_t)bh*SS + j)*DK + d], a);
    cpart[gg][d] = a;
    __syncthreads();
    if (t < 64){
      const float c = cpart[0][t]+cpart[1][t]+cpart[2][t]+cpart[3][t];
      ctx[((size_t)(b*SS + i)*NH + h)*DK + t] = c;
    }
  }
}

// -------------------------------------------------- corner: bh63 rows 0..127
// Reads q/k rows 0..127 from src (q at src, k at src+QKS), stages to LDS,
// then overwrites that region with final att. Single block => race-free.
__global__ __launch_bounds__(256) void attn_corner(
  const float* __restrict__ src, const float* __restrict__ gammas,
  float* __restrict__ att)
{
  __shared__ float lq[128*64];
  __shared__ float lk[128*64];
  const int t = threadIdx.x;
  for (int idx = t; idx < 128*64; idx += 256){
    lq[idx] = src[idx];
    lk[idx] = src[QKS + idx];
  }
  __syncthreads();
  const double sp = softplus64(gammas[15]);
  const int w = t>>6, L = t&63;
  for (int i = w; i < 128; i += 4){
    double s0 = -1e300, s1 = -1e300;
    if (L <= i){
      double a = 0.0;
      for (int d=0; d<64; d++) a = fma((double)lq[i*64+d], (double)lk[L*64+d], a);
      double eff = exp((double)(i-L)*(1.0/21.0)*sp); eff = (eff<1e5)?eff:1e5;
      s0 = a * 0.125 * eff;
    }
    if (64+L <= i){
      double a = 0.0;
      for (int d=0; d<64; d++) a = fma((double)lq[i*64+d], (double)lk[(64+L)*64+d], a);
      double eff = exp((double)(i-64-L)*(1.0/21.0)*sp); eff = (eff<1e5)?eff:1e5;
      s1 = a * 0.125 * eff;
    }
    double mx = (s0>s1)?s0:s1;
    #pragma unroll
    for (int m2=1;m2<64;m2<<=1){ double o2 = __shfl_xor(mx,m2,64); mx = (mx>o2)?mx:o2; }
    double e0 = (L<=i)    ? exp(s0-mx) : 0.0;
    double e1 = (64+L<=i) ? exp(s1-mx) : 0.0;
    double su = e0+e1;
    #pragma unroll
    for (int m2=1;m2<64;m2<<=1) su += __shfl_xor(su,m2,64);
    const double inv = 1.0/su;
    const float p0 = (float)(e0*inv), p1 = (float)(e1*inv);
    float* rb = &att[((size_t)63*SS + i)*SS];
    #pragma unroll
    for (int tt=0; tt<32; tt++)
      rb[tt*64+L] = (tt==0) ? p0 : (tt==1) ? p1 : 0.f;
  }
}

// -------------------------------------------------- layernorm (f32)
__global__ __launch_bounds__(256) void lnorm(
  const float* __restrict__ a, const float* __restrict__ b,
  const float* __restrict__ sc, const float* __restrict__ bi,
  float* __restrict__ out)
{
  __shared__ float red[4];
  const int row = blockIdx.x, tid = threadIdx.x, wid = tid>>6;
  const size_t rb = (size_t)row*D_MODEL;
  float x[4];
  #pragma unroll
  for (int i=0;i<4;i++){
    const int c = tid + i*256;
    x[i] = a[rb+c] + b[rb+c];
  }
  float s = x[0]+x[1]+x[2]+x[3];
  for (int m2=1;m2<64;m2<<=1) s += __shfl_xor(s,m2,64);
  if ((tid&63)==0) red[wid] = s;
  __syncthreads();
  const float mu = (red[0]+red[1]+red[2]+red[3]) * (1.0f/1024.0f);
  __syncthreads();
  float ss2 = 0.f;
  #pragma unroll
  for (int i=0;i<4;i++){ float d = x[i]-mu; ss2 += d*d; }
  for (int m2=1;m2<64;m2<<=1) ss2 += __shfl_xor(ss2,m2,64);
  if ((tid&63)==0) red[wid] = ss2;
  __syncthreads();
  const float var = (red[0]+red[1]+red[2]+red[3]) * (1.0f/1024.0f);
  const float inv = rsqrtf(var + 1e-5f);
  #pragma unroll
  for (int i=0;i<4;i++){
    const int c = tid + i*256;
    out[rb+c] = (x[i]-mu)*inv*sc[c] + bi[c];
  }
}

// ------------------------------------------------------------------ launch
extern "C" void kernel_launch(void* const* d_in, const int* in_sizes, int n_in,
                              void* d_out, int out_size, void* d_ws, size_t ws_size,
                              hipStream_t stream)
{
  const float* query  = (const float*)d_in[0];
  const float* key    = (const float*)d_in[1];
  const float* values = (const float*)d_in[2];
  const float* Wk   = (const float*)d_in[3];
  const float* bk   = (const float*)d_in[4];
  const float* Wv   = (const float*)d_in[5];
  const float* bv   = (const float*)d_in[6];
  const float* Wout = (const float*)d_in[7];
  const float* bout = (const float*)d_in[8];
  const float* gammas = (const float*)d_in[9];
  const float* ln1s = (const float*)d_in[10];
  const float* ln1b = (const float*)d_in[11];
  const float* W1   = (const float*)d_in[12];
  const float* b1   = (const float*)d_in[13];
  const float* W2   = (const float*)d_in[14];
  const float* b2   = (const float*)d_in[15];
  const float* ln2s = (const float*)d_in[16];
  const float* ln2b = (const float*)d_in[17];

  float* outx = (float*)d_out;                 // x: [B,S,1024] f32
  float* att  = outx + (size_t)ROWS*D_MODEL;   // att: [B,H,S,S] f32 (1.07 GB)

  // ---- scratch entirely inside the att region (ZERO d_ws use) ----
  // head scratch: att blocks 0..59 (960 MiB); q/k: att blocks 60..63 (64 MiB)
  char* sc = (char*)att;
  u16* WkTh  = (u16*)(sc +  0*MiB);
  u16* WkTm  = (u16*)(sc +  2*MiB);
  u16* WkTl  = (u16*)(sc +  4*MiB);
  u16* WvTh  = (u16*)(sc +  6*MiB);
  u16* WvTl  = (u16*)(sc +  8*MiB);
  u16* WoTh  = (u16*)(sc + 10*MiB);
  u16* WoTl  = (u16*)(sc + 12*MiB);
  u16* W1Th  = (u16*)(sc + 14*MiB);
  u16* W1Tl  = (u16*)(sc + 22*MiB);
  u16* W2Th  = (u16*)(sc + 30*MiB);
  u16* W2Tl  = (u16*)(sc + 38*MiB);
  float* vbp  = (float*)(sc +  48*MiB);  // [B,H,S,64]   32 MiB
  float* ctxb = (float*)(sc +  80*MiB);  // [B,S,1024]   32 MiB
  float* aof  = (float*)(sc + 112*MiB);  // attn_out     32 MiB
  float* x1f  = (float*)(sc + 144*MiB);  // LN1 out      32 MiB
  float* hbuf = (float*)(sc + 176*MiB);  // FFN hidden  128 MiB
  float* fbuf = (float*)(sc + 304*MiB);  // FFN2 out     32 MiB (ends 336 MiB)
  float* QF = att + 60*BHSZ;             // q head layout [64][2048][64], blocks 60..61
  float* KF = att + 62*BHSZ;             // k head layout, blocks 62..63
  float* D1 = att + 63*BHSZ + 2*(MiB/4)*4;        // block63 rows 1024..1535 (4 MiB)
  float* D2 = att + 63*BHSZ;                      // block63 rows 0..127 (1 MiB)

  dim3 th(256);
  // 1) weight transposes + splits
  twc<<<dim3(32,32),  th, 0, stream>>>(Wk,   WkTh, WkTm, WkTl, 1024, 1024);
  twc<<<dim3(32,32),  th, 0, stream>>>(Wv,   WvTh, WvTl, nullptr, 1024, 1024);
  twc<<<dim3(32,32),  th, 0, stream>>>(Wout, WoTh, WoTl, nullptr, 1024, 1024);
  twc<<<dim3(128,32), th, 0, stream>>>(W1,   W1Th, W1Tl, nullptr, 1024, 4096);
  twc<<<dim3(32,128), th, 0, stream>>>(W2,   W2Th, W2Tl, nullptr, 4096, 1024);
  // 2) projections (q uses Wk/bk per reference!)
  gemm3<<<dim3(8,64), th, 0, stream>>>(query, WkTh, WkTm, WkTl, bk, ROWS, 1024, 1024, QF);
  gemm3<<<dim3(8,64), th, 0, stream>>>(key,   WkTh, WkTm, WkTl, bk, ROWS, 1024, 1024, KF);
  gemm2<<<dim3(8,64), th, 0, stream>>>(values, WvTh, WvTl, bv, ROWS, 1024, 1024, 2, vbp);
  // 3) attention pass A: ctx only
  attn_row<<<dim3(SS,64), th, 0, stream>>>(QF, KF, (long long)QKS, 0, 0,
                                           vbp, gammas, att, ctxb, 0, 1);
  // 4) out-proj + LN1 + FFN + LN2  (x FINAL)
  gemm2<<<dim3(8,64),  th, 0, stream>>>(ctxb, WoTh, WoTl, bout, ROWS, 1024, 1024, 0, aof);
  lnorm<<<dim3(ROWS), th, 0, stream>>>(query, aof, ln1s, ln1b, x1f);
  gemm2<<<dim3(32,64), th, 0, stream>>>(x1f, W1Th, W1Tl, b1, ROWS, 4096, 1024, 1, hbuf);
  gemm2<<<dim3(8,64),  th, 0, stream>>>(hbuf, W2Th, W2Tl, b2, ROWS, 1024, 4096, 0, fbuf);
  lnorm<<<dim3(ROWS), th, 0, stream>>>(x1f, fbuf, ln2s, ln2b, outx);
  // 5) attention pass B: write att. bh 0..59 straight (head scratch now dead).
  attn_row<<<dim3(SS,60), th, 0, stream>>>(QF, KF, (long long)QKS, 0, 0,
                                           vbp, gammas, att, ctxb, 1, 0);
  // 6) bh 60..63: relocate q/k out of the region being written.
  copyf<<<dim3(512), th, 0, stream>>>(D1,            QF + 60*QKS, 4*(long long)QKS);
  copyf<<<dim3(512), th, 0, stream>>>(D1 + 4*QKS,    KF + 60*QKS, 4*(long long)QKS);
  attn_row<<<dim3(SS,3), th, 0, stream>>>(D1, D1 + 4*QKS, (long long)QKS, 60, 0,
                                          vbp, gammas, att, ctxb, 1, 0);
  // bh63 rows 1536..2047 (stash D1 at rows 1024..1535 untouched)
  attn_row<<<dim3(512,1), th, 0, stream>>>(D1 + 3*QKS, D1 + 7*QKS, 0ll, 63, 1536,
                                           vbp, gammas, att, ctxb, 1, 0);
  // sub-stash q63/k63 -> block63 rows 0..127, then rows 128..1535
  copyf<<<dim3(128), th, 0, stream>>>(D2,        D1 + 3*QKS, (long long)QKS);
  copyf<<<dim3(128), th, 0, stream>>>(D2 + QKS,  D1 + 7*QKS, (long long)QKS);
  attn_row<<<dim3(1408,1), th, 0, stream>>>(D2, D2 + QKS, 0ll, 63, 128,
                                            vbp, gammas, att, ctxb, 1, 0);
  // bh63 rows 0..127 via LDS-staged single block (overwrites sub-stash safely)
  attn_corner<<<dim3(1), th, 0, stream>>>(D2, gammas, att);
}

// Round 8
// 12762.866 us; speedup vs baseline: 1.3177x; 1.3177x over previous
//
#include <hip/hip_runtime.h>
#include <math.h>

typedef unsigned short u16;
typedef float f32x4 __attribute__((ext_vector_type(4)));
typedef short s16x8 __attribute__((ext_vector_type(8)));

#define D_MODEL 1024
#define NH 16
#define DK 64
#define DFF 4096
#define BB 4
#define SS 2048
#define ROWS (BB*SS)   // 8192
#define MiB 1048576ull
#define BHSZ 4194304ull   // floats per att[bh] block (2048*2048)
#define QKS  131072ull    // floats per bh slice of q/k (2048*64)

static __device__ __forceinline__ float bf2f(u16 v){
  union{unsigned u; float f;} x; x.u = ((unsigned)v)<<16; return x.f;
}
static __device__ __forceinline__ u16 f2bf(float f){
  union{float f; unsigned u;} x; x.f=f;
  unsigned r = x.u + 0x7fffu + ((x.u>>16)&1u);
  return (u16)(r>>16);
}
static __device__ __forceinline__ double softplus64(float gf){
  double g = (double)gf;
  return (g > 0.0) ? g + log1p(exp(-g)) : log1p(exp(g));
}

// -------------------------------------------------- transpose + f32->bf16 split
__global__ __launch_bounds__(256) void twc(const float* __restrict__ in,
    u16* __restrict__ oh, u16* __restrict__ om, u16* __restrict__ ol, int R, int C){
  __shared__ float t[32][33];
  int c0 = blockIdx.x*32, r0 = blockIdx.y*32;
  int tx = threadIdx.x & 31, ty = threadIdx.x >> 5;
  for (int i=ty; i<32; i+=8) t[i][tx] = in[(size_t)(r0+i)*C + c0 + tx];
  __syncthreads();
  for (int i=ty; i<32; i+=8){
    float x = t[tx][i];
    u16 h = f2bf(x);
    size_t o = (size_t)(c0+i)*R + r0 + tx;
    oh[o] = h;
    if (om){
      float r1 = x - bf2f(h);
      u16 m = f2bf(r1);
      om[o] = m;
      if (ol){ float r2 = r1 - bf2f(m); ol[o] = f2bf(r2); }
    }
  }
}

// -------------------------------------------------- f32 copy
__global__ __launch_bounds__(256) void copyf(float* __restrict__ dst,
                                             const float* __restrict__ src, long long n){
  long long i = (long long)blockIdx.x*256 + threadIdx.x;
  long long stride = (long long)gridDim.x*256;
  for (; i < n; i += stride) dst[i] = src[i];
}

// -------------------------------------------------- triple-split GEMM (Q/K proj)
__global__ __launch_bounds__(256) void gemm3(
    const float* __restrict__ A, const u16* __restrict__ Bh,
    const u16* __restrict__ Bm, const u16* __restrict__ Bl,
    const float* __restrict__ bias, int M, int N, int K, float* __restrict__ o)
{
  __shared__ u16 lAh[128*32], lAm[128*32], lAl[128*32];
  __shared__ u16 lBh[128*32], lBm[128*32], lBl[128*32];
  const int tid = threadIdx.x, wid = tid>>6, L = tid&63;
  const int m0 = blockIdx.y*128, n0 = blockIdx.x*128;
  const int wm = (wid>>1)*64, wn = (wid&1)*64;
  f32x4 acc[4][4] = {};
  const int srow = wid*32 + (L>>2);
  const int scol = (L&3)*8;
  for (int kt=0; kt<K; kt+=32){
    s16x8 ah[2], am[2], al[2], vbh[2], vbm[2], vbl[2];
    #pragma unroll
    for (int rr=0; rr<2; rr++){
      const float* ap = &A[(size_t)(m0 + srow + rr*16)*K + kt + scol];
      #pragma unroll
      for (int e=0;e<8;e++){
        float x = ap[e];
        u16 hh = f2bf(x); float r1 = x - bf2f(hh);
        u16 mm = f2bf(r1); float r2 = r1 - bf2f(mm);
        ah[rr][e] = (short)hh; am[rr][e] = (short)mm; al[rr][e] = (short)f2bf(r2);
      }
      const size_t bo = (size_t)(n0 + srow + rr*16)*K + kt + scol;
      vbh[rr] = *(const s16x8*)&Bh[bo];
      vbm[rr] = *(const s16x8*)&Bm[bo];
      vbl[rr] = *(const s16x8*)&Bl[bo];
    }
    __syncthreads();
    #pragma unroll
    for (int rr=0; rr<2; rr++){
      const int ro = (srow + rr*16)*32 + scol;
      *(s16x8*)&lAh[ro] = ah[rr]; *(s16x8*)&lAm[ro] = am[rr]; *(s16x8*)&lAl[ro] = al[rr];
      *(s16x8*)&lBh[ro] = vbh[rr]; *(s16x8*)&lBm[ro] = vbm[rr]; *(s16x8*)&lBl[ro] = vbl[rr];
    }
    __syncthreads();
    const int lro = (L&15)*32 + (L>>4)*8;
    s16x8 afh[4], afm[4], afl[4], bfh[4], bfm[4], bfl[4];
    #pragma unroll
    for (int t=0;t<4;t++){
      afh[t] = *(const s16x8*)&lAh[(wm + t*16)*32 + lro];
      afm[t] = *(const s16x8*)&lAm[(wm + t*16)*32 + lro];
      afl[t] = *(const s16x8*)&lAl[(wm + t*16)*32 + lro];
      bfh[t] = *(const s16x8*)&lBh[(wn + t*16)*32 + lro];
      bfm[t] = *(const s16x8*)&lBm[(wn + t*16)*32 + lro];
      bfl[t] = *(const s16x8*)&lBl[(wn + t*16)*32 + lro];
    }
    #pragma unroll
    for (int mt=0;mt<4;mt++)
      #pragma unroll
      for (int nt=0;nt<4;nt++){
        f32x4 a2 = acc[mt][nt];
        a2 = __builtin_amdgcn_mfma_f32_16x16x32_bf16(afl[mt], bfh[nt], a2, 0,0,0);
        a2 = __builtin_amdgcn_mfma_f32_16x16x32_bf16(afm[mt], bfm[nt], a2, 0,0,0);
        a2 = __builtin_amdgcn_mfma_f32_16x16x32_bf16(afh[mt], bfl[nt], a2, 0,0,0);
        a2 = __builtin_amdgcn_mfma_f32_16x16x32_bf16(afm[mt], bfh[nt], a2, 0,0,0);
        a2 = __builtin_amdgcn_mfma_f32_16x16x32_bf16(afh[mt], bfm[nt], a2, 0,0,0);
        a2 = __builtin_amdgcn_mfma_f32_16x16x32_bf16(afh[mt], bfh[nt], a2, 0,0,0);
        acc[mt][nt] = a2;
      }
  }
  #pragma unroll
  for (int mt=0;mt<4;mt++)
    #pragma unroll
    for (int nt=0;nt<4;nt++){
      const int gn = n0 + wn + nt*16 + (L&15);
      const float bvv = bias[gn];
      const int gmb = m0 + wm + mt*16 + (L>>4)*4;
      const int h = gn>>6, d = gn&63;
      #pragma unroll
      for (int r=0;r<4;r++){
        const int gm = gmb + r, b = gm>>11, s = gm&2047;
        o[((size_t)(b*NH+h)*SS + s)*DK + d] = acc[mt][nt][r] + bvv;
      }
    }
}

// -------------------------------------------------- pair-split GEMM (~f32 quality)
__global__ __launch_bounds__(256) void gemm2(
    const float* __restrict__ A, const u16* __restrict__ Bh, const u16* __restrict__ Bl,
    const float* __restrict__ bias, int M, int N, int K, int mode, float* __restrict__ o)
{
  __shared__ u16 lAh[128*32], lAl[128*32], lBh[128*32], lBl[128*32];
  const int tid = threadIdx.x, wid = tid>>6, L = tid&63;
  const int m0 = blockIdx.y*128, n0 = blockIdx.x*128;
  const int wm = (wid>>1)*64, wn = (wid&1)*64;
  f32x4 acc[4][4] = {};
  const int srow = wid*32 + (L>>2);
  const int scol = (L&3)*8;
  for (int kt=0; kt<K; kt+=32){
    s16x8 ah[2], al[2], vbh[2], vbl[2];
    #pragma unroll
    for (int rr=0; rr<2; rr++){
      const float* ap = &A[(size_t)(m0 + srow + rr*16)*K + kt + scol];
      #pragma unroll
      for (int e=0;e<8;e++){
        float x = ap[e];
        u16 hh = f2bf(x);
        ah[rr][e] = (short)hh;
        al[rr][e] = (short)f2bf(x - bf2f(hh));
      }
      const size_t bo = (size_t)(n0 + srow + rr*16)*K + kt + scol;
      vbh[rr] = *(const s16x8*)&Bh[bo];
      vbl[rr] = *(const s16x8*)&Bl[bo];
    }
    __syncthreads();
    #pragma unroll
    for (int rr=0; rr<2; rr++){
      const int ro = (srow + rr*16)*32 + scol;
      *(s16x8*)&lAh[ro] = ah[rr]; *(s16x8*)&lAl[ro] = al[rr];
      *(s16x8*)&lBh[ro] = vbh[rr]; *(s16x8*)&lBl[ro] = vbl[rr];
    }
    __syncthreads();
    const int lro = (L&15)*32 + (L>>4)*8;
    s16x8 afh[4], afl[4], bfh[4], bfl[4];
    #pragma unroll
    for (int t=0;t<4;t++){
      afh[t] = *(const s16x8*)&lAh[(wm + t*16)*32 + lro];
      afl[t] = *(const s16x8*)&lAl[(wm + t*16)*32 + lro];
      bfh[t] = *(const s16x8*)&lBh[(wn + t*16)*32 + lro];
      bfl[t] = *(const s16x8*)&lBl[(wn + t*16)*32 + lro];
    }
    #pragma unroll
    for (int mt=0;mt<4;mt++)
      #pragma unroll
      for (int nt=0;nt<4;nt++){
        f32x4 a2 = acc[mt][nt];
        a2 = __builtin_amdgcn_mfma_f32_16x16x32_bf16(afl[mt], bfh[nt], a2, 0,0,0);
        a2 = __builtin_amdgcn_mfma_f32_16x16x32_bf16(afh[mt], bfl[nt], a2, 0,0,0);
        a2 = __builtin_amdgcn_mfma_f32_16x16x32_bf16(afh[mt], bfh[nt], a2, 0,0,0);
        acc[mt][nt] = a2;
      }
  }
  #pragma unroll
  for (int mt=0;mt<4;mt++)
    #pragma unroll
    for (int nt=0;nt<4;nt++){
      const int gn = n0 + wn + nt*16 + (L&15);
      const float bvv = bias[gn];
      const int gmb = m0 + wm + mt*16 + (L>>4)*4;
      #pragma unroll
      for (int r=0;r<4;r++){
        const int gm = gmb + r;
        float v = acc[mt][nt][r] + bvv;
        if (mode==0)      o[(size_t)gm*N + gn] = v;
        else if (mode==1) o[(size_t)gm*N + gn] = fmaxf(v, 0.f);
        else {
          const int b = gm>>11, s = gm&2047, h = gn>>6, d = gn&63;
          o[((size_t)(b*NH+h)*SS + s)*DK + d] = v;
        }
      }
    }
}

// -------------------------------------------------- attention row kernel (v2)
// f64 dot + LDS eff table (f64, ~264 exps/block) + f32 softmax-exp.
// Scores in registers; f32 p[] in LDS only for cross-thread PV reads.
__global__ __launch_bounds__(256) void attn_row(
  const float* __restrict__ q, const float* __restrict__ k, long long qs,
  int bh0, int row0,
  const float* __restrict__ vb, const float* __restrict__ gammas,
  float* __restrict__ att, float* __restrict__ ctx, int wa, int wc)
{
  __shared__ double sq[64];
  __shared__ double effs[SS];     // 0.125 * min(exp(c*delta), 1e5)
  __shared__ double pw[8];
  __shared__ float  p[SS];        // normalized probs (cross-thread)
  __shared__ double red[4];
  __shared__ float  cpart[4][64];
  const int i = row0 + blockIdx.x;
  const int bh = bh0 + blockIdx.y, h = bh&15, b = bh>>4;
  const int t = threadIdx.x, wid = t>>6, L = t&63;
  const double c = softplus64(gammas[h]) * (1.0/21.0);

  if (t < 64) sq[t] = (double)q[(size_t)blockIdx.y*qs + (size_t)i*DK + t];
  if (t < 8)  pw[t] = exp(c * 256.0 * (double)t);
  const double base = exp(c * (double)t);
  __syncthreads();
  for (int qq = 0; qq*256 + t <= i; qq++){
    double e = base * pw[qq];
    effs[qq*256 + t] = ((e < 1e5) ? e : 1e5) * 0.125;
  }
  __syncthreads();

  // scores (registers) + running max
  double sv[8];
  double lmax = -1e300;
  int nj = 0;
  for (int j = t; j <= i; j += 256, nj++){
    const f32x4* kr = (const f32x4*)&k[(size_t)blockIdx.y*qs + (size_t)j*DK];
    double a0=0.0, a1=0.0, a2=0.0, a3=0.0;
    #pragma unroll
    for (int d4=0; d4<16; d4++){
      f32x4 kv = kr[d4];
      a0 = fma((double)kv[0], sq[d4*4+0], a0);
      a1 = fma((double)kv[1], sq[d4*4+1], a1);
      a2 = fma((double)kv[2], sq[d4*4+2], a2);
      a3 = fma((double)kv[3], sq[d4*4+3], a3);
    }
    const double s = ((a0+a1)+(a2+a3)) * effs[i-j];
    sv[nj] = s;
    lmax = (lmax > s) ? lmax : s;
  }
  #pragma unroll
  for (int m2=1;m2<64;m2<<=1){ double o2 = __shfl_xor(lmax,m2,64); lmax = (lmax>o2)?lmax:o2; }
  if (L==0) red[wid] = lmax;
  __syncthreads();
  double m = red[0];
  m = (m>red[1])?m:red[1]; m = (m>red[2])?m:red[2]; m = (m>red[3])?m:red[3];
  __syncthreads();

  // exp (f32) + sum
  float ev[8];
  double lsum = 0.0;
  nj = 0;
  for (int j = t; j <= i; j += 256, nj++){
    float e = expf((float)(sv[nj] - m));
    ev[nj] = e;
    lsum += (double)e;
  }
  #pragma unroll
  for (int m2=1;m2<64;m2<<=1) lsum += __shfl_xor(lsum,m2,64);
  if (L==0) red[wid] = lsum;
  __syncthreads();
  const float inv = (float)(1.0 / (red[0]+red[1]+red[2]+red[3]));
  nj = 0;
  for (int j = t; j <= i; j += 256, nj++) p[j] = ev[nj]*inv;
  __syncthreads();

  if (wa){
    float* rb = &att[((size_t)bh*SS + i)*SS];
    for (int j = t; j < SS; j += 256)
      rb[j] = (j <= i) ? p[j] : 0.f;
  }
  if (wc){
    const int gg = t>>6, d = t&63;
    const float* vr = &vb[(size_t)bh*SS*DK + d];
    float a0=0.f, a1=0.f, a2=0.f, a3=0.f;
    int j = gg;
    for (; j+12 <= i; j += 16){
      a0 = fmaf(p[j   ], vr[(size_t)(j   )*DK], a0);
      a1 = fmaf(p[j+ 4], vr[(size_t)(j+ 4)*DK], a1);
      a2 = fmaf(p[j+ 8], vr[(size_t)(j+ 8)*DK], a2);
      a3 = fmaf(p[j+12], vr[(size_t)(j+12)*DK], a3);
    }
    for (; j <= i; j += 4) a0 = fmaf(p[j], vr[(size_t)j*DK], a0);
    cpart[gg][d] = (a0+a1)+(a2+a3);
    __syncthreads();
    if (t < 64){
      const float cc = cpart[0][t]+cpart[1][t]+cpart[2][t]+cpart[3][t];
      ctx[((size_t)(b*SS + i)*NH + h)*DK + t] = cc;
    }
  }
}

// -------------------------------------------------- corner: bh63 rows 0..127
__global__ __launch_bounds__(256) void attn_corner(
  const float* __restrict__ src, const float* __restrict__ gammas,
  float* __restrict__ att)
{
  __shared__ float lq[128*64];
  __shared__ float lk[128*64];
  const int t = threadIdx.x;
  for (int idx = t; idx < 128*64; idx += 256){
    lq[idx] = src[idx];
    lk[idx] = src[QKS + idx];
  }
  __syncthreads();
  const double sp = softplus64(gammas[15]);
  const int w = t>>6, L = t&63;
  for (int i = w; i < 128; i += 4){
    double s0 = -1e300, s1 = -1e300;
    if (L <= i){
      double a = 0.0;
      for (int d=0; d<64; d++) a = fma((double)lq[i*64+d], (double)lk[L*64+d], a);
      double eff = exp((double)(i-L)*(1.0/21.0)*sp); eff = (eff<1e5)?eff:1e5;
      s0 = a * 0.125 * eff;
    }
    if (64+L <= i){
      double a = 0.0;
      for (int d=0; d<64; d++) a = fma((double)lq[i*64+d], (double)lk[(64+L)*64+d], a);
      double eff = exp((double)(i-64-L)*(1.0/21.0)*sp); eff = (eff<1e5)?eff:1e5;
      s1 = a * 0.125 * eff;
    }
    double mx = (s0>s1)?s0:s1;
    #pragma unroll
    for (int m2=1;m2<64;m2<<=1){ double o2 = __shfl_xor(mx,m2,64); mx = (mx>o2)?mx:o2; }
    double e0 = (L<=i)    ? exp(s0-mx) : 0.0;
    double e1 = (64+L<=i) ? exp(s1-mx) : 0.0;
    double su = e0+e1;
    #pragma unroll
    for (int m2=1;m2<64;m2<<=1) su += __shfl_xor(su,m2,64);
    const double inv = 1.0/su;
    const float p0 = (float)(e0*inv), p1 = (float)(e1*inv);
    float* rb = &att[((size_t)63*SS + i)*SS];
    #pragma unroll
    for (int tt=0; tt<32; tt++)
      rb[tt*64+L] = (tt==0) ? p0 : (tt==1) ? p1 : 0.f;
  }
}

// -------------------------------------------------- layernorm (f32)
__global__ __launch_bounds__(256) void lnorm(
  const float* __restrict__ a, const float* __restrict__ b,
  const float* __restrict__ sc, const float* __restrict__ bi,
  float* __restrict__ out)
{
  __shared__ float red[4];
  const int row = blockIdx.x, tid = threadIdx.x, wid = tid>>6;
  const size_t rb = (size_t)row*D_MODEL;
  float x[4];
  #pragma unroll
  for (int i=0;i<4;i++){
    const int c = tid + i*256;
    x[i] = a[rb+c] + b[rb+c];
  }
  float s = x[0]+x[1]+x[2]+x[3];
  for (int m2=1;m2<64;m2<<=1) s += __shfl_xor(s,m2,64);
  if ((tid&63)==0) red[wid] = s;
  __syncthreads();
  const float mu = (red[0]+red[1]+red[2]+red[3]) * (1.0f/1024.0f);
  __syncthreads();
  float ss2 = 0.f;
  #pragma unroll
  for (int i=0;i<4;i++){ float d = x[i]-mu; ss2 += d*d; }
  for (int m2=1;m2<64;m2<<=1) ss2 += __shfl_xor(ss2,m2,64);
  if ((tid&63)==0) red[wid] = ss2;
  __syncthreads();
  const float var = (red[0]+red[1]+red[2]+red[3]) * (1.0f/1024.0f);
  const float inv = rsqrtf(var + 1e-5f);
  #pragma unroll
  for (int i=0;i<4;i++){
    const int c = tid + i*256;
    out[rb+c] = (x[i]-mu)*inv*sc[c] + bi[c];
  }
}

// ------------------------------------------------------------------ launch
extern "C" void kernel_launch(void* const* d_in, const int* in_sizes, int n_in,
                              void* d_out, int out_size, void* d_ws, size_t ws_size,
                              hipStream_t stream)
{
  const float* query  = (const float*)d_in[0];
  const float* key    = (const float*)d_in[1];
  const float* values = (const float*)d_in[2];
  const float* Wk   = (const float*)d_in[3];
  const float* bk   = (const float*)d_in[4];
  const float* Wv   = (const float*)d_in[5];
  const float* bv   = (const float*)d_in[6];
  const float* Wout = (const float*)d_in[7];
  const float* bout = (const float*)d_in[8];
  const float* gammas = (const float*)d_in[9];
  const float* ln1s = (const float*)d_in[10];
  const float* ln1b = (const float*)d_in[11];
  const float* W1   = (const float*)d_in[12];
  const float* b1   = (const float*)d_in[13];
  const float* W2   = (const float*)d_in[14];
  const float* b2   = (const float*)d_in[15];
  const float* ln2s = (const float*)d_in[16];
  const float* ln2b = (const float*)d_in[17];

  float* outx = (float*)d_out;
  float* att  = outx + (size_t)ROWS*D_MODEL;

  char* sc = (char*)att;
  u16* WkTh  = (u16*)(sc +  0*MiB);
  u16* WkTm  = (u16*)(sc +  2*MiB);
  u16* WkTl  = (u16*)(sc +  4*MiB);
  u16* WvTh  = (u16*)(sc +  6*MiB);
  u16* WvTl  = (u16*)(sc +  8*MiB);
  u16* WoTh  = (u16*)(sc + 10*MiB);
  u16* WoTl  = (u16*)(sc + 12*MiB);
  u16* W1Th  = (u16*)(sc + 14*MiB);
  u16* W1Tl  = (u16*)(sc + 22*MiB);
  u16* W2Th  = (u16*)(sc + 30*MiB);
  u16* W2Tl  = (u16*)(sc + 38*MiB);
  float* vbp  = (float*)(sc +  48*MiB);
  float* ctxb = (float*)(sc +  80*MiB);
  float* aof  = (float*)(sc + 112*MiB);
  float* x1f  = (float*)(sc + 144*MiB);
  float* hbuf = (float*)(sc + 176*MiB);
  float* fbuf = (float*)(sc + 304*MiB);
  float* QF = att + 60*BHSZ;
  float* KF = att + 62*BHSZ;
  float* D1 = att + 63*BHSZ + 2*(MiB/4)*4;
  float* D2 = att + 63*BHSZ;

  dim3 th(256);
  twc<<<dim3(32,32),  th, 0, stream>>>(Wk,   WkTh, WkTm, WkTl, 1024, 1024);
  twc<<<dim3(32,32),  th, 0, stream>>>(Wv,   WvTh, WvTl, nullptr, 1024, 1024);
  twc<<<dim3(32,32),  th, 0, stream>>>(Wout, WoTh, WoTl, nullptr, 1024, 1024);
  twc<<<dim3(128,32), th, 0, stream>>>(W1,   W1Th, W1Tl, nullptr, 1024, 4096);
  twc<<<dim3(32,128), th, 0, stream>>>(W2,   W2Th, W2Tl, nullptr, 4096, 1024);
  gemm3<<<dim3(8,64), th, 0, stream>>>(query, WkTh, WkTm, WkTl, bk, ROWS, 1024, 1024, QF);
  gemm3<<<dim3(8,64), th, 0, stream>>>(key,   WkTh, WkTm, WkTl, bk, ROWS, 1024, 1024, KF);
  gemm2<<<dim3(8,64), th, 0, stream>>>(values, WvTh, WvTl, bv, ROWS, 1024, 1024, 2, vbp);
  // attention pass A: ctx only
  attn_row<<<dim3(SS,64), th, 0, stream>>>(QF, KF, (long long)QKS, 0, 0,
                                           vbp, gammas, att, ctxb, 0, 1);
  gemm2<<<dim3(8,64),  th, 0, stream>>>(ctxb, WoTh, WoTl, bout, ROWS, 1024, 1024, 0, aof);
  lnorm<<<dim3(ROWS), th, 0, stream>>>(query, aof, ln1s, ln1b, x1f);
  gemm2<<<dim3(32,64), th, 0, stream>>>(x1f, W1Th, W1Tl, b1, ROWS, 4096, 1024, 1, hbuf);
  gemm2<<<dim3(8,64),  th, 0, stream>>>(hbuf, W2Th, W2Tl, b2, ROWS, 1024, 4096, 0, fbuf);
  lnorm<<<dim3(ROWS), th, 0, stream>>>(x1f, fbuf, ln2s, ln2b, outx);
  // attention pass B: write att
  attn_row<<<dim3(SS,60), th, 0, stream>>>(QF, KF, (long long)QKS, 0, 0,
                                           vbp, gammas, att, ctxb, 1, 0);
  copyf<<<dim3(512), th, 0, stream>>>(D1,            QF + 60*QKS, 4*(long long)QKS);
  copyf<<<dim3(512), th, 0, stream>>>(D1 + 4*QKS,    KF + 60*QKS, 4*(long long)QKS);
  attn_row<<<dim3(SS,3), th, 0, stream>>>(D1, D1 + 4*QKS, (long long)QKS, 60, 0,
                                          vbp, gammas, att, ctxb, 1, 0);
  attn_row<<<dim3(512,1), th, 0, stream>>>(D1 + 3*QKS, D1 + 7*QKS, 0ll, 63, 1536,
                                           vbp, gammas, att, ctxb, 1, 0);
  copyf<<<dim3(128), th, 0, stream>>>(D2,        D1 + 3*QKS, (long long)QKS);
  copyf<<<dim3(128), th, 0, stream>>>(D2 + QKS,  D1 + 7*QKS, (long long)QKS);
  attn_row<<<dim3(1408,1), th, 0, stream>>>(D2, D2 + QKS, 0ll, 63, 128,
                                            vbp, gammas, att, ctxb, 1, 0);
  attn_corner<<<dim3(1), th, 0, stream>>>(D2, gammas, att);
}